// Round 14
// baseline (3724.713 us; speedup 1.0000x reference)
//
#include <hip/hip_runtime.h>
#include <math.h>

// Problem constants
#define BN   128      // batch
#define TN   1440     // timesteps
#define HN   512      // hidden
#define GBn  8        // batch groups
#define BSn  16       // batches per group
#define GCn  32       // column groups
#define HCn  16       // h-cols per WG
#define WST  536      // LDS row stride in f16: 268 dw == 12 mod 32 -> conflict-free b128 frag reads

using f16 = _Float16;
typedef f16   f16x8 __attribute__((ext_vector_type(8)));
typedef float f32x4 __attribute__((ext_vector_type(4)));
typedef unsigned int       uint32;
typedef unsigned long long u64;

// ws layout (bytes):
//   [0,1024)             flags[8][32] int
//   [1024,2048)          scal: [0]=half_tau, [1]=trigger
//   [2048,526336)        hbufP uint32 [2 buf][128 b][512 k]  (lo16=f16 hi, hi16=f16 lo*2048)
//   [526336,1263616)     xsf f32 [128][1440]
#define OFF_SCAL 1024
#define OFF_HBUF 2048
#define OFF_XSF  (2048 + 2 * BN * HN * 4)

// ---------------- K0: scalar prep (grads -> half_tau, trigger) ----------------
__global__ void k_prep(const float* __restrict__ w_ih, float* __restrict__ scal) {
    __shared__ float ssum[4];
    float s = 0.0f;
    for (int i = threadIdx.x; i < 3 * HN * 2; i += 256) s += w_ih[i];
    for (int o = 32; o >= 1; o >>= 1) s += __shfl_down(s, o, 64);
    if ((threadIdx.x & 63) == 0) ssum[threadIdx.x >> 6] = s;
    __syncthreads();
    if (threadIdx.x == 0) {
        float tot = ssum[0] + ssum[1] + ssum[2] + ssum[3];
        float grads = tot / 3072.0f - 1.0f;
        float tau_new = 6.0f + grads * 0.1f;
        bool trig = (tau_new >= 1.0f) && (tau_new != 6.0f);
        scal[0] = rintf(tau_new * 0.5f);   // round-half-even matches jnp.round
        scal[1] = trig ? 1.0f : 0.0f;
    }
}

// ---------------- K1: NaN-fix + belief_fill (one wave per batch row) ----------------
__global__ void k_fill(const float* __restrict__ inp, const float* __restrict__ scal,
                       float* __restrict__ xsf) {
    const int b = blockIdx.x;
    const int lane = threadIdx.x;            // 0..63
    const float ht = scal[0];
    const bool trig = scal[1] != 0.0f;
    const float* xrow = inp + (size_t)b * 3 * TN;       // channel 0 = xs
    const float* mrow = xrow + 2 * TN;                   // channel 2 = mask
    const int CH = 23;                                   // 64*23 = 1472 >= 1440
    const int start = lane * CH;

    if (!trig) {
        for (int i = 0; i < CH; ++i) {
            int t = start + i;
            if (t < TN) { float x = xrow[t]; if (x != x) x = -1.0f; xsf[(size_t)b * TN + t] = x; }
        }
        return;
    }
    int pm = -1;
#pragma unroll
    for (int i = 0; i < CH; ++i) { int t = start + i; if (t < TN && mrow[t] == 1.0f) pm = t; }
    int incl = pm;
    for (int o = 1; o < 64; o <<= 1) { int v = __shfl_up(incl, o, 64); if (lane >= o) incl = max(incl, v); }
    int pexcl = __shfl_up(incl, 1, 64); if (lane == 0) pexcl = -1;
    int nm = TN;
#pragma unroll
    for (int i = CH - 1; i >= 0; --i) { int t = start + i; if (t < TN && mrow[t] == 1.0f) nm = t; }
    int incl2 = nm;
    for (int o = 1; o < 64; o <<= 1) { int v = __shfl_down(incl2, o, 64); if (lane + o < 64) incl2 = min(incl2, v); }
    int nexcl = __shfl_down(incl2, 1, 64); if (lane == 63) nexcl = TN;
    int narr[23];
    int runn = nexcl;
#pragma unroll
    for (int i = CH - 1; i >= 0; --i) {
        int t = start + i;
        if (t < TN) { if (mrow[t] == 1.0f) runn = t; narr[i] = runn; } else narr[i] = TN;
    }
    int runp = pexcl;
#pragma unroll
    for (int i = 0; i < CH; ++i) {
        int t = start + i;
        if (t >= TN) break;
        float x = xrow[t]; if (x != x) x = -1.0f;
        if (mrow[t] == 1.0f) runp = t;
        int pv = runp, nv = narr[i];
        int pc = min(max(pv, 0), TN - 1), nc = min(max(nv, 0), TN - 1);
        float xp = xrow[pc]; if (xp != xp) xp = -1.0f;
        float xn = xrow[nc]; if (xn != xn) xn = -1.0f;
        bool use_n = (nv < TN) && ((float)t >= (float)nv - ht);
        bool use_p = (pv >= 0) && ((float)t <= (float)pv + ht);
        float o = use_n ? xn : (use_p ? xp : x);
        xsf[(size_t)b * TN + t] = o;
    }
}

// ---------------- K2: persistent column-split GRU, L3-coherent comm ----------------
// grid 256 = 8 batch-groups x 32 col-groups; block 256 (4 waves); 1 WG/CU.
// Protocol (publish store, drain-barrier B3 + tid0 flag, scopes, gb=bid&7 mapping):
// byte-identical to R0/R9/R13 -- frozen by 13 rounds of evidence.
// R13 (kept): K-split waves -- wave wv computes ALL 3 gates over K-slice
// [128wv,128wv+128), partials via sPart, 4 SIMDs busy. Measured -160cy/step.
// R14 (new, compute-repartition only):
//  (a) PER-WAVE staging + B1 DELETED: wave wv stages exactly its own K-quarter
//      (rows 0..15, u64-cols [64wv,64wv+64), still 64-lane-consecutive = 512B/instr
//      coalesced). Its MFMA reads only that region -> staging->MFMA dependency is
//      intra-wave; program order + compiler lgkmcnt orders it. Waves run
//      poll->load->stage->MFMA fully decoupled; only B2 (sPart cross-wave) and B3
//      (protocol) remain. Next-iter sH overwrite is same-wave (program order safe);
//      next-iter sPart overwrite happens after B3 (all gate reads done).
//  (b) poll is per-wave-exact (REQUIRED by (a)): wave wv consumes f16 cols
//      [128wv,128wv+128) = producers [8wv,8wv+8) only (R10-proven pattern).
//  (c) accl dependent-MFMA chain split 8-deep -> 2x 4-deep (R9 mechanism, +12 VGPR).
__global__ __launch_bounds__(256, 1) void k_gru(
    const float* __restrict__ inp, const float* __restrict__ w_ih,
    const float* __restrict__ w_hh, const float* __restrict__ b_ih,
    const float* __restrict__ b_hh, const float* __restrict__ w_fc,
    const float* __restrict__ b_fc, const float* __restrict__ xsf,
    uint32* __restrict__ hbufP, int* __restrict__ flags, float* __restrict__ out) {
    __shared__ __align__(16) f16 sHhi[BSn * WST];
    __shared__ __align__(16) f16 sHlo[BSn * WST];
    __shared__ float sPart[3][4][BSn][HCn + 1];   // [gate][wave][batch-row][col(+pad)]
    __shared__ float sWi0[48], sWi1[48], sBias[48];

    const int tid = threadIdx.x;
    const int gb = blockIdx.x & 7;
    const int gc = blockIdx.x >> 3;
    const int lane = tid & 63;
    const int wv   = tid >> 6;        // K-slice owner: k in [128wv, 128wv+128)
    const int bs   = tid >> 4;        // gate-math row 0..15
    const int j    = tid & 15;
    const int bglob = gb * BSn + bs;
    const int pcol  = gc * HCn + j;
    const int frow = lane & 15;       // MFMA m (A) / n (B) index
    const int kgrp = lane >> 4;       // MFMA k-group
    const int scol = 64 * wv + lane;  // staging u64-col owned by this thread

    if (tid < 48) {
        int gate = tid >> 4, jj = tid & 15;
        int grow = gate * HN + gc * HCn + jj;
        sWi0[tid]  = w_ih[grow * 2 + 0];
        sWi1[tid]  = w_ih[grow * 2 + 1];
        sBias[tid] = b_ih[grow] + b_hh[grow];
    }

    // one-time: weight B-fragments into VGPRs (hi + lo*2^11 split).
    // wave wv, gate g, chunk kc: K-offset 128wv + 32kc + 8kgrp.
    f16x8 bfh[3][4], bfl[3][4];
#pragma unroll
    for (int g = 0; g < 3; ++g) {
        const float* wrow = w_hh + (size_t)(g * HN + gc * HCn + frow) * HN;
#pragma unroll
        for (int kc = 0; kc < 4; ++kc) {
            const int k0 = 128 * wv + 32 * kc + 8 * kgrp;
#pragma unroll
            for (int u = 0; u < 8; ++u) {
                float w = wrow[k0 + u];
                f16 hi = (f16)w;
                bfh[g][kc][u] = hi;
                bfl[g][kc][u] = (f16)((w - (float)hi) * 2048.0f);
            }
        }
    }
    __syncthreads();

    int* myflags = flags + gb * GCn;
    const f16x8* pAhi = (const f16x8*)(sHhi + frow * WST);
    const f16x8* pAlo = (const f16x8*)(sHlo + frow * WST);
    float h = 0.0f;

    for (int t = 0; t < TN; ++t) {
        // prefetch driving inputs (independent of sync)
        float xsv = xsf[(size_t)bglob * TN + t];
        float mkv = inp[((size_t)bglob * 3 + 2) * TN + t];
        // 1. wave wv polls ONLY its 8 producers (f16 cols [128wv,128wv+128) ->
        //    gc in [8wv,8wv+8)); waves fully decoupled until B2
        if (lane < 8) {
            while (__hip_atomic_load(&myflags[8 * wv + lane], __ATOMIC_RELAXED,
                                     __HIP_MEMORY_SCOPE_AGENT) < t) {}
        }
        // 2. per-wave staging of OWN K-quarter: row i, u64-col scol (64 consecutive
        //    u64/wave = 512B per instruction, coalesced as before). No barrier after:
        //    this wave's MFMA reads only this wave's writes (lgkmcnt orders them).
        {
            const u64* src64 = (const u64*)(hbufP + ((size_t)(t & 1) * BN + gb * BSn) * HN);
            u64 hv[16];
#pragma unroll
            for (int i = 0; i < 16; ++i)
                hv[i] = __hip_atomic_load(src64 + (size_t)i * (HN / 2) + scol,
                                          __ATOMIC_RELAXED, __HIP_MEMORY_SCOPE_AGENT);
#pragma unroll
            for (int i = 0; i < 16; ++i) {
                uint32 d0 = (uint32)hv[i], d1 = (uint32)(hv[i] >> 32);
                ((uint32*)(sHhi + i * WST))[scol] = __builtin_amdgcn_perm(d1, d0, 0x05040100u);
                ((uint32*)(sHlo + i * WST))[scol] = __builtin_amdgcn_perm(d1, d0, 0x07060302u);
            }
        }
        // 3. MFMA: wave wv: 3 gates x K-slice [128wv,128wv+128) = 36 MFMAs.
        //    acch chains 4-deep; accl split into two 4-deep chains (R14c).
        {
            f32x4 acch[3] = {{0.f,0.f,0.f,0.f},{0.f,0.f,0.f,0.f},{0.f,0.f,0.f,0.f}};
            f32x4 acl1[3] = {{0.f,0.f,0.f,0.f},{0.f,0.f,0.f,0.f},{0.f,0.f,0.f,0.f}};
            f32x4 acl2[3] = {{0.f,0.f,0.f,0.f},{0.f,0.f,0.f,0.f},{0.f,0.f,0.f,0.f}};
#pragma unroll
            for (int kc = 0; kc < 4; ++kc) {
                f16x8 ah = pAhi[16 * wv + kc * 4 + kgrp];
                f16x8 al = pAlo[16 * wv + kc * 4 + kgrp];
#pragma unroll
                for (int g = 0; g < 3; ++g) {
                    acch[g] = __builtin_amdgcn_mfma_f32_16x16x32_f16(ah, bfh[g][kc], acch[g], 0, 0, 0);
                    acl1[g] = __builtin_amdgcn_mfma_f32_16x16x32_f16(ah, bfl[g][kc], acl1[g], 0, 0, 0);
                    acl2[g] = __builtin_amdgcn_mfma_f32_16x16x32_f16(al, bfh[g][kc], acl2[g], 0, 0, 0);
                }
            }
            // C/D: row=(lane>>4)*4+r (batch), col=lane&15 (j)
#pragma unroll
            for (int g = 0; g < 3; ++g)
#pragma unroll
                for (int r = 0; r < 4; ++r)
                    sPart[g][wv][kgrp * 4 + r][frow] =
                        acch[g][r] + (acl1[g][r] + acl2[g][r]) * (1.0f / 2048.0f);
        }
        __syncthreads();                                   // B2: sPart visible
        // 4. fast-math gate math (sum 4 wave-partials) + publish h_{t+1} slice
        {
            float ghr = sPart[0][0][bs][j] + sPart[0][1][bs][j]
                      + sPart[0][2][bs][j] + sPart[0][3][bs][j];
            float ghz = sPart[1][0][bs][j] + sPart[1][1][bs][j]
                      + sPart[1][2][bs][j] + sPart[1][3][bs][j];
            float ghn = sPart[2][0][bs][j] + sPart[2][1][bs][j]
                      + sPart[2][2][bs][j] + sPart[2][3][bs][j];
            float gir = xsv * sWi0[j]      + mkv * sWi1[j]      + sBias[j];
            float giz = xsv * sWi0[16 + j] + mkv * sWi1[16 + j] + sBias[16 + j];
            float gin = xsv * sWi0[32 + j] + mkv * sWi1[32 + j] + sBias[32 + j];
            float rg = __fdividef(1.0f, 1.0f + __expf(-(gir + ghr)));
            float zg = __fdividef(1.0f, 1.0f + __expf(-(giz + ghz)));
            float xt = gin + rg * ghn;
            float ng = __fdividef(2.0f, 1.0f + __expf(-2.0f * xt)) - 1.0f;  // tanh(xt)
            h = (1.0f - zg) * ng + zg * h;
            f16 hi = (f16)h;
            f16 lo = (f16)((h - (float)hi) * 2048.0f);
            uint32 pk = (uint32)__builtin_bit_cast(unsigned short, hi)
                      | ((uint32)__builtin_bit_cast(unsigned short, lo) << 16);
            __hip_atomic_store(&hbufP[((size_t)((t + 1) & 1) * BN + bglob) * HN + pcol], pk,
                               __ATOMIC_RELAXED, __HIP_MEMORY_SCOPE_AGENT);
        }
        __syncthreads();   // B3: drains vmcnt(0) before s_barrier -> publishes acked at L3
        if (tid == 0)
            __hip_atomic_store(&myflags[gc], t + 1, __ATOMIC_RELAXED, __HIP_MEMORY_SCOPE_AGENT);
    }
    // 5. final FC: out[b] = sum_k h[b][k]*w_fc[k] + b_fc
    float part = h * w_fc[pcol];
#pragma unroll
    for (int o = 1; o < 16; o <<= 1) part += __shfl_xor(part, o, 64);
    if (j == 0) {
        if (gc == 0) part += b_fc[0];
        atomicAdd(&out[bglob], part);
    }
}

extern "C" void kernel_launch(void* const* d_in, const int* in_sizes, int n_in,
                              void* d_out, int out_size, void* d_ws, size_t ws_size,
                              hipStream_t stream) {
    const float* inp  = (const float*)d_in[0];
    const float* w_ih = (const float*)d_in[1];
    const float* w_hh = (const float*)d_in[2];
    const float* b_ih = (const float*)d_in[3];
    const float* b_hh = (const float*)d_in[4];
    const float* w_fc = (const float*)d_in[5];
    const float* b_fc = (const float*)d_in[6];
    float* out = (float*)d_out;
    char* ws = (char*)d_ws;
    int*    flags = (int*)ws;
    float*  scal  = (float*)(ws + OFF_SCAL);
    uint32* hbufP = (uint32*)(ws + OFF_HBUF);
    float*  xsf   = (float*)(ws + OFF_XSF);

    // zero: flags + scal + packed-h buf0 (= h_0 = 0); d_out (atomicAdd target)
    hipMemsetAsync(ws, 0, OFF_HBUF + BN * HN * 4, stream);
    hipMemsetAsync(d_out, 0, BN * sizeof(float), stream);
    k_prep<<<1, 256, 0, stream>>>(w_ih, scal);
    k_fill<<<BN, 64, 0, stream>>>(inp, scal, xsf);
    k_gru<<<GBn * GCn, 256, 0, stream>>>(inp, w_ih, w_hh, b_ih, b_hh, w_fc, b_fc,
                                         xsf, hbufP, flags, out);
}

// Round 15
// 3705.658 us; speedup vs baseline: 1.0051x; 1.0051x over previous
//
#include <hip/hip_runtime.h>
#include <math.h>

// Problem constants
#define BN   128      // batch
#define TN   1440     // timesteps
#define HN   512      // hidden
#define GBn  8        // batch groups
#define BSn  16       // batches per group
#define GCn  32       // column groups
#define HCn  16       // h-cols per WG
#define WST  536      // LDS row stride in f16: 268 dw == 12 mod 32 -> conflict-free b128 frag reads

using f16 = _Float16;
typedef f16   f16x8 __attribute__((ext_vector_type(8)));
typedef float f32x4 __attribute__((ext_vector_type(4)));
typedef unsigned int       uint32;
typedef unsigned long long u64;

// ws layout (bytes):
//   [0,1024)             flags[8][32] int
//   [1024,2048)          scal: [0]=half_tau, [1]=trigger
//   [2048,526336)        hbufP uint32 [2 buf][128 b][512 k]  (lo16=f16 hi, hi16=f16 lo*2048)
//   [526336,1263616)     xsf f32 [128][1440]
#define OFF_SCAL 1024
#define OFF_HBUF 2048
#define OFF_XSF  (2048 + 2 * BN * HN * 4)

// ---------------- K0: scalar prep (grads -> half_tau, trigger) ----------------
__global__ void k_prep(const float* __restrict__ w_ih, float* __restrict__ scal) {
    __shared__ float ssum[4];
    float s = 0.0f;
    for (int i = threadIdx.x; i < 3 * HN * 2; i += 256) s += w_ih[i];
    for (int o = 32; o >= 1; o >>= 1) s += __shfl_down(s, o, 64);
    if ((threadIdx.x & 63) == 0) ssum[threadIdx.x >> 6] = s;
    __syncthreads();
    if (threadIdx.x == 0) {
        float tot = ssum[0] + ssum[1] + ssum[2] + ssum[3];
        float grads = tot / 3072.0f - 1.0f;
        float tau_new = 6.0f + grads * 0.1f;
        bool trig = (tau_new >= 1.0f) && (tau_new != 6.0f);
        scal[0] = rintf(tau_new * 0.5f);   // round-half-even matches jnp.round
        scal[1] = trig ? 1.0f : 0.0f;
    }
}

// ---------------- K1: NaN-fix + belief_fill (one wave per batch row) ----------------
__global__ void k_fill(const float* __restrict__ inp, const float* __restrict__ scal,
                       float* __restrict__ xsf) {
    const int b = blockIdx.x;
    const int lane = threadIdx.x;            // 0..63
    const float ht = scal[0];
    const bool trig = scal[1] != 0.0f;
    const float* xrow = inp + (size_t)b * 3 * TN;       // channel 0 = xs
    const float* mrow = xrow + 2 * TN;                   // channel 2 = mask
    const int CH = 23;                                   // 64*23 = 1472 >= 1440
    const int start = lane * CH;

    if (!trig) {
        for (int i = 0; i < CH; ++i) {
            int t = start + i;
            if (t < TN) { float x = xrow[t]; if (x != x) x = -1.0f; xsf[(size_t)b * TN + t] = x; }
        }
        return;
    }
    int pm = -1;
#pragma unroll
    for (int i = 0; i < CH; ++i) { int t = start + i; if (t < TN && mrow[t] == 1.0f) pm = t; }
    int incl = pm;
    for (int o = 1; o < 64; o <<= 1) { int v = __shfl_up(incl, o, 64); if (lane >= o) incl = max(incl, v); }
    int pexcl = __shfl_up(incl, 1, 64); if (lane == 0) pexcl = -1;
    int nm = TN;
#pragma unroll
    for (int i = CH - 1; i >= 0; --i) { int t = start + i; if (t < TN && mrow[t] == 1.0f) nm = t; }
    int incl2 = nm;
    for (int o = 1; o < 64; o <<= 1) { int v = __shfl_down(incl2, o, 64); if (lane + o < 64) incl2 = min(incl2, v); }
    int nexcl = __shfl_down(incl2, 1, 64); if (lane == 63) nexcl = TN;
    int narr[23];
    int runn = nexcl;
#pragma unroll
    for (int i = CH - 1; i >= 0; --i) {
        int t = start + i;
        if (t < TN) { if (mrow[t] == 1.0f) runn = t; narr[i] = runn; } else narr[i] = TN;
    }
    int runp = pexcl;
#pragma unroll
    for (int i = 0; i < CH; ++i) {
        int t = start + i;
        if (t >= TN) break;
        float x = xrow[t]; if (x != x) x = -1.0f;
        if (mrow[t] == 1.0f) runp = t;
        int pv = runp, nv = narr[i];
        int pc = min(max(pv, 0), TN - 1), nc = min(max(nv, 0), TN - 1);
        float xp = xrow[pc]; if (xp != xp) xp = -1.0f;
        float xn = xrow[nc]; if (xn != xn) xn = -1.0f;
        bool use_n = (nv < TN) && ((float)t >= (float)nv - ht);
        bool use_p = (pv >= 0) && ((float)t <= (float)pv + ht);
        float o = use_n ? xn : (use_p ? xp : x);
        xsf[(size_t)b * TN + t] = o;
    }
}

// ---------------- K2: persistent column-split GRU, L3-coherent comm ----------------
// grid 256 = 8 batch-groups x 32 col-groups; block 256 (4 waves); 1 WG/CU.
// Protocol (poll, coalesced u64 staging, B1/B2/B3 barriers, vmcnt-drain before tid0
// flag, gb=bid&7 XCD-local mapping, scopes): byte-identical to R13 (measured best,
// 3665us). 14 rounds of evidence: protocol frozen; compute-repartitions only.
// R13 (kept): K-split waves -- wave wv computes ALL 3 gates over K-slice
// [128wv,128wv+128); partials via sPart; 4 SIMDs busy.
// R15 (new, both zero-risk):
//  (a) final-step tail skip: at t==TN-1 the publish/drain/flag have no consumer
//      (FC uses register h) -- skip one full exchange tail.
//  (b) accl dependent-MFMA chain split 8-deep -> 2x 4-deep (R9's proven mechanism,
//      isolated this time; +12 VGPR, occupancy unchanged at 1 WG/CU).
__global__ __launch_bounds__(256, 1) void k_gru(
    const float* __restrict__ inp, const float* __restrict__ w_ih,
    const float* __restrict__ w_hh, const float* __restrict__ b_ih,
    const float* __restrict__ b_hh, const float* __restrict__ w_fc,
    const float* __restrict__ b_fc, const float* __restrict__ xsf,
    uint32* __restrict__ hbufP, int* __restrict__ flags, float* __restrict__ out) {
    __shared__ __align__(16) f16 sHhi[BSn * WST];
    __shared__ __align__(16) f16 sHlo[BSn * WST];
    __shared__ float sPart[3][4][BSn][HCn + 1];   // [gate][wave][batch-row][col(+pad)]
    __shared__ float sWi0[48], sWi1[48], sBias[48];

    const int tid = threadIdx.x;
    const int gb = blockIdx.x & 7;
    const int gc = blockIdx.x >> 3;
    const int lane = tid & 63;
    const int wv   = tid >> 6;        // K-slice owner: k in [128wv, 128wv+128)
    const int bs   = tid >> 4;        // gate-math row 0..15
    const int j    = tid & 15;
    const int bglob = gb * BSn + bs;
    const int pcol  = gc * HCn + j;
    const int frow = lane & 15;       // MFMA m (A) / n (B) index
    const int kgrp = lane >> 4;       // MFMA k-group

    if (tid < 48) {
        int gate = tid >> 4, jj = tid & 15;
        int grow = gate * HN + gc * HCn + jj;
        sWi0[tid]  = w_ih[grow * 2 + 0];
        sWi1[tid]  = w_ih[grow * 2 + 1];
        sBias[tid] = b_ih[grow] + b_hh[grow];
    }

    // one-time: weight B-fragments into VGPRs (hi + lo*2^11 split).
    // wave wv, gate g, chunk kc: K-offset 128wv + 32kc + 8kgrp.
    f16x8 bfh[3][4], bfl[3][4];
#pragma unroll
    for (int g = 0; g < 3; ++g) {
        const float* wrow = w_hh + (size_t)(g * HN + gc * HCn + frow) * HN;
#pragma unroll
        for (int kc = 0; kc < 4; ++kc) {
            const int k0 = 128 * wv + 32 * kc + 8 * kgrp;
#pragma unroll
            for (int u = 0; u < 8; ++u) {
                float w = wrow[k0 + u];
                f16 hi = (f16)w;
                bfh[g][kc][u] = hi;
                bfl[g][kc][u] = (f16)((w - (float)hi) * 2048.0f);
            }
        }
    }
    __syncthreads();

    int* myflags = flags + gb * GCn;
    const f16x8* pAhi = (const f16x8*)(sHhi + frow * WST);
    const f16x8* pAlo = (const f16x8*)(sHlo + frow * WST);
    float h = 0.0f;

    for (int t = 0; t < TN; ++t) {
        // prefetch driving inputs (independent of sync)
        float xsv = xsf[(size_t)bglob * TN + t];
        float mkv = inp[((size_t)bglob * 3 + 2) * TN + t];
        // 1. every wave polls all 32 peer flags (relaxed atomic load = L3 read)
        if (lane < GCn) {
            while (__hip_atomic_load(&myflags[lane], __ATOMIC_RELAXED, __HIP_MEMORY_SCOPE_AGENT) < t) {}
        }
        // 2. stage h_t into LDS: 16 coherent u64 loads/thread (2 packed dwords of batch row i)
        {
            const uint32* src = hbufP + ((size_t)(t & 1) * BN + gb * BSn) * HN;
            u64 hv[16];
#pragma unroll
            for (int i = 0; i < 16; ++i)
                hv[i] = __hip_atomic_load((const u64*)(src + (size_t)i * HN) + tid,
                                          __ATOMIC_RELAXED, __HIP_MEMORY_SCOPE_AGENT);
#pragma unroll
            for (int i = 0; i < 16; ++i) {
                uint32 d0 = (uint32)hv[i], d1 = (uint32)(hv[i] >> 32);
                ((uint32*)(sHhi + i * WST))[tid] = __builtin_amdgcn_perm(d1, d0, 0x05040100u);
                ((uint32*)(sHlo + i * WST))[tid] = __builtin_amdgcn_perm(d1, d0, 0x07060302u);
            }
        }
        __syncthreads();                                   // B1: sH visible
        // 3. MFMA: ALL 4 waves work. Wave wv: 3 gates x K-slice [128wv,128wv+128)
        //    = 36 MFMAs; acch 4-deep, accl split into two 4-deep chains (R15b).
        {
            f32x4 acch[3] = {{0.f,0.f,0.f,0.f},{0.f,0.f,0.f,0.f},{0.f,0.f,0.f,0.f}};
            f32x4 acl1[3] = {{0.f,0.f,0.f,0.f},{0.f,0.f,0.f,0.f},{0.f,0.f,0.f,0.f}};
            f32x4 acl2[3] = {{0.f,0.f,0.f,0.f},{0.f,0.f,0.f,0.f},{0.f,0.f,0.f,0.f}};
#pragma unroll
            for (int kc = 0; kc < 4; ++kc) {
                f16x8 ah = pAhi[16 * wv + kc * 4 + kgrp];
                f16x8 al = pAlo[16 * wv + kc * 4 + kgrp];
#pragma unroll
                for (int g = 0; g < 3; ++g) {
                    acch[g] = __builtin_amdgcn_mfma_f32_16x16x32_f16(ah, bfh[g][kc], acch[g], 0, 0, 0);
                    acl1[g] = __builtin_amdgcn_mfma_f32_16x16x32_f16(ah, bfl[g][kc], acl1[g], 0, 0, 0);
                    acl2[g] = __builtin_amdgcn_mfma_f32_16x16x32_f16(al, bfh[g][kc], acl2[g], 0, 0, 0);
                }
            }
            // C/D: row=(lane>>4)*4+r (batch), col=lane&15 (j)
#pragma unroll
            for (int g = 0; g < 3; ++g)
#pragma unroll
                for (int r = 0; r < 4; ++r)
                    sPart[g][wv][kgrp * 4 + r][frow] =
                        acch[g][r] + (acl1[g][r] + acl2[g][r]) * (1.0f / 2048.0f);
        }
        __syncthreads();                                   // B2: sPart visible
        // 4. fast-math gate math (sum 4 wave-partials) + publish h_{t+1} slice
        {
            float ghr = sPart[0][0][bs][j] + sPart[0][1][bs][j]
                      + sPart[0][2][bs][j] + sPart[0][3][bs][j];
            float ghz = sPart[1][0][bs][j] + sPart[1][1][bs][j]
                      + sPart[1][2][bs][j] + sPart[1][3][bs][j];
            float ghn = sPart[2][0][bs][j] + sPart[2][1][bs][j]
                      + sPart[2][2][bs][j] + sPart[2][3][bs][j];
            float gir = xsv * sWi0[j]      + mkv * sWi1[j]      + sBias[j];
            float giz = xsv * sWi0[16 + j] + mkv * sWi1[16 + j] + sBias[16 + j];
            float gin = xsv * sWi0[32 + j] + mkv * sWi1[32 + j] + sBias[32 + j];
            float rg = __fdividef(1.0f, 1.0f + __expf(-(gir + ghr)));
            float zg = __fdividef(1.0f, 1.0f + __expf(-(giz + ghz)));
            float xt = gin + rg * ghn;
            float ng = __fdividef(2.0f, 1.0f + __expf(-2.0f * xt)) - 1.0f;  // tanh(xt)
            h = (1.0f - zg) * ng + zg * h;
            // R15a: final step's h_TN has no consumer -- skip publish/drain/flag
            if (t + 1 < TN) {
                f16 hi = (f16)h;
                f16 lo = (f16)((h - (float)hi) * 2048.0f);
                uint32 pk = (uint32)__builtin_bit_cast(unsigned short, hi)
                          | ((uint32)__builtin_bit_cast(unsigned short, lo) << 16);
                __hip_atomic_store(&hbufP[((size_t)((t + 1) & 1) * BN + bglob) * HN + pcol], pk,
                                   __ATOMIC_RELAXED, __HIP_MEMORY_SCOPE_AGENT);
            }
        }
        if (t + 1 < TN) {
            __syncthreads();   // B3: drains vmcnt(0) before s_barrier -> publishes acked at L3
            if (tid == 0)
                __hip_atomic_store(&myflags[gc], t + 1, __ATOMIC_RELAXED, __HIP_MEMORY_SCOPE_AGENT);
        }
    }
    // 5. final FC: out[b] = sum_k h[b][k]*w_fc[k] + b_fc
    float part = h * w_fc[pcol];
#pragma unroll
    for (int o = 1; o < 16; o <<= 1) part += __shfl_xor(part, o, 64);
    if (j == 0) {
        if (gc == 0) part += b_fc[0];
        atomicAdd(&out[bglob], part);
    }
}

extern "C" void kernel_launch(void* const* d_in, const int* in_sizes, int n_in,
                              void* d_out, int out_size, void* d_ws, size_t ws_size,
                              hipStream_t stream) {
    const float* inp  = (const float*)d_in[0];
    const float* w_ih = (const float*)d_in[1];
    const float* w_hh = (const float*)d_in[2];
    const float* b_ih = (const float*)d_in[3];
    const float* b_hh = (const float*)d_in[4];
    const float* w_fc = (const float*)d_in[5];
    const float* b_fc = (const float*)d_in[6];
    float* out = (float*)d_out;
    char* ws = (char*)d_ws;
    int*    flags = (int*)ws;
    float*  scal  = (float*)(ws + OFF_SCAL);
    uint32* hbufP = (uint32*)(ws + OFF_HBUF);
    float*  xsf   = (float*)(ws + OFF_XSF);

    // zero: flags + scal + packed-h buf0 (= h_0 = 0); d_out (atomicAdd target)
    hipMemsetAsync(ws, 0, OFF_HBUF + BN * HN * 4, stream);
    hipMemsetAsync(d_out, 0, BN * sizeof(float), stream);
    k_prep<<<1, 256, 0, stream>>>(w_ih, scal);
    k_fill<<<BN, 64, 0, stream>>>(inp, scal, xsf);
    k_gru<<<GBn * GCn, 256, 0, stream>>>(inp, w_ih, w_hh, b_ih, b_hh, w_fc, b_fc,
                                         xsf, hbufP, flags, out);
}